// Round 3
// baseline (15180.608 us; speedup 1.0000x reference)
//
#include <hip/hip_runtime.h>
#include <hip/hip_bf16.h>

#define B_ 2
#define S_ 1024
#define H_ 1024
#define NH_ 16
#define NKV_ 4
#define HD_ 64
#define T_ (B_*S_)
#define E_ 64
#define TOPK_ 8
#define IE_ 512
#define IS_ 1408
#define EPS_ 1e-6f

// ---------------- RMSNorm: out[t,:] = x * rsqrt(mean(x^2)+eps) * w ----------------
__global__ __launch_bounds__(256) void rmsnorm_kernel(
    const float* __restrict__ xin, const float* __restrict__ w,
    float* __restrict__ out)
{
    int t = blockIdx.x, tid = threadIdx.x;
    __shared__ float red[256];
    float4 xv = ((const float4*)(xin + (size_t)t * H_))[tid];
    float ss = xv.x*xv.x + xv.y*xv.y + xv.z*xv.z + xv.w*xv.w;
    red[tid] = ss; __syncthreads();
    for (int s = 128; s > 0; s >>= 1) { if (tid < s) red[tid] += red[tid + s]; __syncthreads(); }
    float inv = 1.0f / sqrtf(red[0] / (float)H_ + EPS_);
    float4 wv = ((const float4*)w)[tid];
    float4 o;
    o.x = xv.x*inv*wv.x; o.y = xv.y*inv*wv.y;
    o.z = xv.z*inv*wv.z; o.w = xv.w*inv*wv.w;
    ((float4*)(out + (size_t)t * H_))[tid] = o;
}

// ---------------- GEMM: C[M,N] = A[M,K] @ W[N,K]^T (+bias) (+res) ----------------
// 64x64 tile, 256 threads, 4x4 per thread, K-chunk 16. M%64==0, N%64==0, K%16==0.
template<int BIAS, int RES>
__global__ __launch_bounds__(256) void gemm_kernel(
    const float* __restrict__ A, const float* __restrict__ W,
    const float* __restrict__ bias, const float* __restrict__ res,
    float* __restrict__ C, int M, int N, int K)
{
    __shared__ float As[16][68];   // [kk][m]
    __shared__ float Bs[16][68];   // [kk][n]
    int tid = threadIdx.x;
    int bm = blockIdx.y, bn = blockIdx.x;
    int tx = tid & 15, ty = tid >> 4;
    int lc = tid & 15, lrb = tid >> 4;
    const float* Ab = A + (size_t)bm * 64 * K;
    const float* Wb = W + (size_t)bn * 64 * K;
    float c[4][4] = {};
    for (int k0 = 0; k0 < K; k0 += 16) {
#pragma unroll
        for (int rr = 0; rr < 4; ++rr) {
            int r = lrb + rr * 16;
            As[lc][r] = Ab[(size_t)r * K + k0 + lc];
            Bs[lc][r] = Wb[(size_t)r * K + k0 + lc];
        }
        __syncthreads();
#pragma unroll
        for (int kk = 0; kk < 16; ++kk) {
            float4 av = *(const float4*)&As[kk][ty * 4];
            float4 bv = *(const float4*)&Bs[kk][tx * 4];
            float aa[4] = {av.x, av.y, av.z, av.w};
            float bb[4] = {bv.x, bv.y, bv.z, bv.w};
#pragma unroll
            for (int i = 0; i < 4; ++i)
#pragma unroll
                for (int j = 0; j < 4; ++j)
                    c[i][j] += aa[i] * bb[j];
        }
        __syncthreads();
    }
#pragma unroll
    for (int i = 0; i < 4; ++i) {
        int row = bm * 64 + ty * 4 + i;
        int col0 = bn * 64 + tx * 4;
        float vv[4];
#pragma unroll
        for (int j = 0; j < 4; ++j) {
            float v = c[i][j];
            if (BIAS) v += bias[col0 + j];
            if (RES)  v += res[(size_t)row * N + col0 + j];
            vv[j] = v;
        }
        float4 cv; cv.x = vv[0]; cv.y = vv[1]; cv.z = vv[2]; cv.w = vv[3];
        *(float4*)&C[(size_t)row * N + col0] = cv;
    }
}

// ---------------- RoPE in place on [T, nh*64] f32, pos = t % S ----------------
__global__ __launch_bounds__(256) void rope_kernel(float* __restrict__ x, int nh)
{
    int gid = blockIdx.x * 256 + threadIdx.x;
    int total = T_ * nh * 32;
    if (gid >= total) return;
    int d = gid & 31;
    int h = (gid >> 5) % nh;
    int t = gid / (32 * nh);
    int pos = t & (S_ - 1);
    float inv = expf(-(float)d * (13.815510557964274f / 32.0f));  // 1e6^(-d/32)
    float f = (float)pos * inv;
    float sn, cs;
    sincosf(f, &sn, &cs);
    size_t base = (size_t)t * nh * 64 + (size_t)h * 64 + d;
    float x1 = x[base], x2 = x[base + 32];
    x[base]      = x1 * cs - x2 * sn;
    x[base + 32] = x2 * cs + x1 * sn;
}

// ---------------- Causal GQA attention: one wave per (b,h,query) row ----------------
__global__ __launch_bounds__(64) void attn_kernel(
    const float* __restrict__ q, const float* __restrict__ k, const float* __restrict__ v,
    float* __restrict__ o)
{
    int s = blockIdx.x, h = blockIdx.y, b = blockIdx.z;
    int lane = threadIdx.x;
    int kvh = h >> 2;
    __shared__ float qs[64];
    __shared__ float ol[64][65];
    const float* qrow = q + ((size_t)(b * S_ + s)) * (NH_ * HD_) + h * HD_;
    qs[lane] = qrow[lane] * 0.125f;   // 1/sqrt(64)
    __syncthreads();
    float qr[64];
#pragma unroll
    for (int d = 0; d < 64; ++d) qr[d] = qs[d];
    float m = -INFINITY, l = 0.f;
    float oacc[64];
#pragma unroll
    for (int d = 0; d < 64; ++d) oacc[d] = 0.f;
    for (int j = lane; j <= s; j += 64) {
        const float* krow = k + ((size_t)(b * S_ + j)) * (NKV_ * HD_) + kvh * HD_;
        float sc = 0.f;
#pragma unroll
        for (int d = 0; d < 64; ++d) sc += qr[d] * krow[d];
        if (sc > m) {
            float rr = expf(m - sc);
            l *= rr;
#pragma unroll
            for (int d = 0; d < 64; ++d) oacc[d] *= rr;
            m = sc;
        }
        float p = expf(sc - m);
        l += p;
        const float* vrow = v + ((size_t)(b * S_ + j)) * (NKV_ * HD_) + kvh * HD_;
#pragma unroll
        for (int d = 0; d < 64; ++d) oacc[d] += p * vrow[d];
    }
    float M = m;
#pragma unroll
    for (int off = 32; off; off >>= 1) M = fmaxf(M, __shfl_xor(M, off));
    float rr = expf(m - M);          // m==-inf -> 0
    float lw = l * rr;
    float L = lw;
#pragma unroll
    for (int off = 32; off; off >>= 1) L += __shfl_xor(L, off);
#pragma unroll
    for (int d = 0; d < 64; ++d) ol[lane][d] = oacc[d] * rr;
    __syncthreads();
    float sum = 0.f;
#pragma unroll
    for (int i = 0; i < 64; ++i) sum += ol[i][lane];
    o[((size_t)(b * S_ + s)) * (NH_ * HD_) + h * HD_ + lane] = sum / L;
}

// ---------------- Router softmax + top-8 (tie -> lowest index) + renorm ----------------
__global__ __launch_bounds__(64) void topk_kernel(
    const float* __restrict__ logits, float* __restrict__ topw, int* __restrict__ topi)
{
    int t = blockIdx.x; int e = threadIdx.x;
    float lg = logits[(size_t)t * E_ + e];
    float M = lg;
#pragma unroll
    for (int off = 32; off; off >>= 1) M = fmaxf(M, __shfl_xor(M, off));
    float ex = expf(lg - M);
    float Ssum = ex;
#pragma unroll
    for (int off = 32; off; off >>= 1) Ssum += __shfl_xor(Ssum, off);
    float pcur = ex / Ssum;
    float wsum = 0.f;
    float selw[TOPK_]; int seli[TOPK_];
    for (int r = 0; r < TOPK_; ++r) {
        float v = pcur; int idx = e;
#pragma unroll
        for (int off = 32; off; off >>= 1) {
            float v2 = __shfl_xor(v, off);
            int i2 = __shfl_xor(idx, off);
            if (v2 > v || (v2 == v && i2 < idx)) { v = v2; idx = i2; }
        }
        selw[r] = v; seli[r] = idx; wsum += v;
        if (e == idx) pcur = -1.f;
    }
    if (e < TOPK_) {
        topw[(size_t)t * TOPK_ + e] = selw[e] / wsum;
        topi[(size_t)t * TOPK_ + e] = seli[e];
    }
}

// ---------------- Sparse MoE: one block per token, 8 experts sequentially ----------------
__global__ __launch_bounds__(256) void moe_kernel(
    const float* __restrict__ y, const int* __restrict__ topi, const float* __restrict__ topw,
    const float* __restrict__ wg, const float* __restrict__ wu,
    const float* __restrict__ wd, float* __restrict__ out)
{
    int t = blockIdx.x, tid = threadIdx.x;
    __shared__ float ys[H_];
    __shared__ float inter[IE_];
    {
        float4 yv = ((const float4*)(y + (size_t)t * H_))[tid];
        ys[tid * 4 + 0] = yv.x; ys[tid * 4 + 1] = yv.y;
        ys[tid * 4 + 2] = yv.z; ys[tid * 4 + 3] = yv.w;
    }
    float oacc[4] = {0.f, 0.f, 0.f, 0.f};
    __syncthreads();
    for (int r = 0; r < TOPK_; ++r) {
        int e = topi[t * TOPK_ + r];
        float w = topw[t * TOPK_ + r];
        const float2* g2 = (const float2*)(wg + (size_t)e * H_ * IE_);
        const float2* u2 = (const float2*)(wu + (size_t)e * H_ * IE_);
        float ag0 = 0, ag1 = 0, au0 = 0, au1 = 0;
#pragma unroll 4
        for (int h = 0; h < H_; ++h) {
            float yv = ys[h];
            float2 gv = g2[h * (IE_ / 2) + tid];
            float2 uv = u2[h * (IE_ / 2) + tid];
            ag0 += yv * gv.x; ag1 += yv * gv.y;
            au0 += yv * uv.x; au1 += yv * uv.y;
        }
        inter[tid * 2 + 0] = ag0 / (1.f + expf(-ag0)) * au0;
        inter[tid * 2 + 1] = ag1 / (1.f + expf(-ag1)) * au1;
        __syncthreads();
        const float* d = wd + (size_t)e * IE_ * H_;
#pragma unroll 2
        for (int i = 0; i < IE_; ++i) {
            float iv = inter[i] * w;
            float4 dv = ((const float4*)(d + (size_t)i * H_))[tid];
            oacc[0] += iv * dv.x; oacc[1] += iv * dv.y;
            oacc[2] += iv * dv.z; oacc[3] += iv * dv.w;
        }
        __syncthreads();
    }
    float4 ov; ov.x = oacc[0]; ov.y = oacc[1]; ov.z = oacc[2]; ov.w = oacc[3];
    ((float4*)(out + (size_t)t * H_))[tid] = ov;
}

// ---------------- elementwise silu(g)*u -> g ----------------
__global__ __launch_bounds__(256) void silu_mul_kernel(
    float* __restrict__ g, const float* __restrict__ u, int n)
{
    int i = blockIdx.x * 256 + threadIdx.x;
    if (i < n) {
        float x = g[i];
        g[i] = x / (1.f + expf(-x)) * u[i];
    }
}

// ---------------- final: out = h_mid + moe + sigmoid(y.shg)*shexp (f32 store) ----------------
__global__ __launch_bounds__(256) void combine_kernel(
    const float* __restrict__ hmid, const float* __restrict__ moe,
    const float* __restrict__ shexp, const float* __restrict__ y,
    const float* __restrict__ shg_w, float* __restrict__ out)
{
    int t = blockIdx.x, tid = threadIdx.x;
    __shared__ float red[256];
    float4 yv = ((const float4*)(y + (size_t)t * H_))[tid];
    float4 wv = ((const float4*)shg_w)[tid];
    float part = yv.x * wv.x + yv.y * wv.y + yv.z * wv.z + yv.w * wv.w;
    red[tid] = part; __syncthreads();
    for (int s = 128; s > 0; s >>= 1) { if (tid < s) red[tid] += red[tid + s]; __syncthreads(); }
    float sig = 1.f / (1.f + expf(-red[0]));
    size_t base = (size_t)t * H_ + (size_t)tid * 4;
    float4 hm = *(const float4*)(hmid + base);
    float4 mo = *(const float4*)(moe + base);
    float4 sh = *(const float4*)(shexp + base);
    float4 o;
    o.x = hm.x + mo.x + sig * sh.x;
    o.y = hm.y + mo.y + sig * sh.y;
    o.z = hm.z + mo.z + sig * sh.z;
    o.w = hm.w + mo.w + sig * sh.w;
    ((float4*)out)[(size_t)t * (H_ / 4) + tid] = o;
}

extern "C" void kernel_launch(void* const* d_in, const int* in_sizes, int n_in,
                              void* d_out, int out_size, void* d_ws, size_t ws_size,
                              hipStream_t stream)
{
    const float* hs       = (const float*)d_in[0];
    const float* ln1_w    = (const float*)d_in[1];
    const float* ln2_w    = (const float*)d_in[2];
    const float* q_w      = (const float*)d_in[3];
    const float* q_b      = (const float*)d_in[4];
    const float* k_w      = (const float*)d_in[5];
    const float* k_b      = (const float*)d_in[6];
    const float* v_w      = (const float*)d_in[7];
    const float* v_b      = (const float*)d_in[8];
    const float* o_w      = (const float*)d_in[9];
    const float* gate_w   = (const float*)d_in[10];
    const float* w_gate   = (const float*)d_in[11];
    const float* w_up     = (const float*)d_in[12];
    const float* w_down   = (const float*)d_in[13];
    const float* s_gate_w = (const float*)d_in[14];
    const float* s_up_w   = (const float*)d_in[15];
    const float* s_down_w = (const float*)d_in[16];
    const float* sh_gate_w= (const float*)d_in[17];

    float* wsf = (float*)d_ws;
    size_t offA = 0;                           // xn (T*H) then sg (T*IS)
    size_t offB = offA + (size_t)T_ * IS_;     // q (T*H) then su (T*IS)
    size_t offC = offB + (size_t)T_ * IS_;     // attn_out (T*H) then shexp (T*H)
    size_t offD = offC + (size_t)T_ * H_;      // k (T*256)
    size_t offE = offD + (size_t)T_ * 256;     // v (T*256)
    size_t offF = offE + (size_t)T_ * 256;     // h_mid (T*H)
    size_t offG = offF + (size_t)T_ * H_;      // y (T*H)
    size_t offH = offG + (size_t)T_ * H_;      // moe_out (T*H)
    size_t offI = offH + (size_t)T_ * H_;      // logits (T*E)
    size_t offJ = offI + (size_t)T_ * E_;      // topw (T*8)
    size_t offK = offJ + (size_t)T_ * TOPK_;   // topi (T*8, int)

    float* xn     = wsf + offA;
    float* sg     = wsf + offA;
    float* qb     = wsf + offB;
    float* su     = wsf + offB;
    float* ao     = wsf + offC;
    float* shexp  = wsf + offC;
    float* kb     = wsf + offD;
    float* vb     = wsf + offE;
    float* hmid   = wsf + offF;
    float* yb     = wsf + offG;
    float* moe    = wsf + offH;
    float* logits = wsf + offI;
    float* topw   = wsf + offJ;
    int*   topi   = (int*)(wsf + offK);

    (void)in_sizes; (void)n_in; (void)out_size; (void)ws_size;

    // 1. rmsnorm1
    rmsnorm_kernel<<<T_, 256, 0, stream>>>(hs, ln1_w, xn);
    // 2-4. q/k/v projections (+bias)
    gemm_kernel<1,0><<<dim3(16, 32), 256, 0, stream>>>(xn, q_w, q_b, nullptr, qb, T_, 1024, 1024);
    gemm_kernel<1,0><<<dim3(4, 32), 256, 0, stream>>>(xn, k_w, k_b, nullptr, kb, T_, 256, 1024);
    gemm_kernel<1,0><<<dim3(4, 32), 256, 0, stream>>>(xn, v_w, v_b, nullptr, vb, T_, 256, 1024);
    // 5-6. RoPE
    rope_kernel<<<(T_ * NH_ * 32 + 255) / 256, 256, 0, stream>>>(qb, NH_);
    rope_kernel<<<(T_ * NKV_ * 32 + 255) / 256, 256, 0, stream>>>(kb, NKV_);
    // 7. attention
    attn_kernel<<<dim3(S_, NH_, B_), 64, 0, stream>>>(qb, kb, vb, ao);
    // 8. o_proj + residual
    gemm_kernel<0,1><<<dim3(16, 32), 256, 0, stream>>>(ao, o_w, nullptr, hs, hmid, T_, 1024, 1024);
    // 9. rmsnorm2
    rmsnorm_kernel<<<T_, 256, 0, stream>>>(hmid, ln2_w, yb);
    // 10. router logits
    gemm_kernel<0,0><<<dim3(1, 32), 256, 0, stream>>>(yb, gate_w, nullptr, nullptr, logits, T_, 64, 1024);
    // 11. softmax + top8
    topk_kernel<<<T_, 64, 0, stream>>>(logits, topw, topi);
    // 12. sparse MoE experts
    moe_kernel<<<T_, 256, 0, stream>>>(yb, topi, topw, w_gate, w_up, w_down, moe);
    // 13-16. shared expert
    gemm_kernel<0,0><<<dim3(22, 32), 256, 0, stream>>>(yb, s_gate_w, nullptr, nullptr, sg, T_, IS_, 1024);
    gemm_kernel<0,0><<<dim3(22, 32), 256, 0, stream>>>(yb, s_up_w, nullptr, nullptr, su, T_, IS_, 1024);
    silu_mul_kernel<<<(T_ * IS_ + 255) / 256, 256, 0, stream>>>(sg, su, T_ * IS_);
    gemm_kernel<0,0><<<dim3(16, 32), 256, 0, stream>>>(sg, s_down_w, nullptr, nullptr, shexp, T_, H_, IS_);
    // 17. combine + f32 store
    combine_kernel<<<T_, 256, 0, stream>>>(hmid, moe, shexp, yb, sh_gate_w, (float*)d_out);
}

// Round 4
// 3499.136 us; speedup vs baseline: 4.3384x; 4.3384x over previous
//
#include <hip/hip_runtime.h>
#include <hip/hip_bf16.h>

#define B_ 2
#define S_ 1024
#define H_ 1024
#define NH_ 16
#define NKV_ 4
#define HD_ 64
#define T_ (B_*S_)
#define E_ 64
#define TOPK_ 8
#define IE_ 512
#define IS_ 1408
#define EPS_ 1e-6f
#define MAXTILES 320

// ---------------- RMSNorm ----------------
__global__ __launch_bounds__(256) void rmsnorm_kernel(
    const float* __restrict__ xin, const float* __restrict__ w,
    float* __restrict__ out)
{
    int t = blockIdx.x, tid = threadIdx.x;
    __shared__ float red[256];
    float4 xv = ((const float4*)(xin + (size_t)t * H_))[tid];
    float ss = xv.x*xv.x + xv.y*xv.y + xv.z*xv.z + xv.w*xv.w;
    red[tid] = ss; __syncthreads();
    for (int s = 128; s > 0; s >>= 1) { if (tid < s) red[tid] += red[tid + s]; __syncthreads(); }
    float inv = 1.0f / sqrtf(red[0] / (float)H_ + EPS_);
    float4 wv = ((const float4*)w)[tid];
    float4 o;
    o.x = xv.x*inv*wv.x; o.y = xv.y*inv*wv.y;
    o.z = xv.z*inv*wv.z; o.w = xv.w*inv*wv.w;
    ((float4*)(out + (size_t)t * H_))[tid] = o;
}

// ---------------- dense GEMM: C[M,N] = A[M,K] @ W[N,K]^T (+bias) (+res) ----------------
template<int BIAS, int RES>
__global__ __launch_bounds__(256) void gemm_kernel(
    const float* __restrict__ A, const float* __restrict__ W,
    const float* __restrict__ bias, const float* __restrict__ res,
    float* __restrict__ C, int M, int N, int K)
{
    __shared__ float As[16][68];
    __shared__ float Bs[16][68];
    int tid = threadIdx.x;
    int bm = blockIdx.y, bn = blockIdx.x;
    int tx = tid & 15, ty = tid >> 4;
    int lc = tid & 15, lrb = tid >> 4;
    const float* Ab = A + (size_t)bm * 64 * K;
    const float* Wb = W + (size_t)bn * 64 * K;
    float c[4][4] = {};
    for (int k0 = 0; k0 < K; k0 += 16) {
#pragma unroll
        for (int rr = 0; rr < 4; ++rr) {
            int r = lrb + rr * 16;
            As[lc][r] = Ab[(size_t)r * K + k0 + lc];
            Bs[lc][r] = Wb[(size_t)r * K + k0 + lc];
        }
        __syncthreads();
#pragma unroll
        for (int kk = 0; kk < 16; ++kk) {
            float4 av = *(const float4*)&As[kk][ty * 4];
            float4 bv = *(const float4*)&Bs[kk][tx * 4];
            float aa[4] = {av.x, av.y, av.z, av.w};
            float bb[4] = {bv.x, bv.y, bv.z, bv.w};
#pragma unroll
            for (int i = 0; i < 4; ++i)
#pragma unroll
                for (int j = 0; j < 4; ++j)
                    c[i][j] += aa[i] * bb[j];
        }
        __syncthreads();
    }
#pragma unroll
    for (int i = 0; i < 4; ++i) {
        int row = bm * 64 + ty * 4 + i;
        int col0 = bn * 64 + tx * 4;
        float vv[4];
#pragma unroll
        for (int j = 0; j < 4; ++j) {
            float v = c[i][j];
            if (BIAS) v += bias[col0 + j];
            if (RES)  v += res[(size_t)row * N + col0 + j];
            vv[j] = v;
        }
        float4 cv; cv.x = vv[0]; cv.y = vv[1]; cv.z = vv[2]; cv.w = vv[3];
        *(float4*)&C[(size_t)row * N + col0] = cv;
    }
}

// ---------------- RoPE ----------------
__global__ __launch_bounds__(256) void rope_kernel(float* __restrict__ x, int nh)
{
    int gid = blockIdx.x * 256 + threadIdx.x;
    int total = T_ * nh * 32;
    if (gid >= total) return;
    int d = gid & 31;
    int h = (gid >> 5) % nh;
    int t = gid / (32 * nh);
    int pos = t & (S_ - 1);
    float inv = expf(-(float)d * (13.815510557964274f / 32.0f));
    float f = (float)pos * inv;
    float sn, cs;
    sincosf(f, &sn, &cs);
    size_t base = (size_t)t * nh * 64 + (size_t)h * 64 + d;
    float x1 = x[base], x2 = x[base + 32];
    x[base]      = x1 * cs - x2 * sn;
    x[base + 32] = x2 * cs + x1 * sn;
}

// ---------------- attention: one wave per (b,h,query) ----------------
__global__ __launch_bounds__(64) void attn_kernel(
    const float* __restrict__ q, const float* __restrict__ k, const float* __restrict__ v,
    float* __restrict__ o)
{
    int s = blockIdx.x, h = blockIdx.y, b = blockIdx.z;
    int lane = threadIdx.x;
    int kvh = h >> 2;
    __shared__ float qs[64];
    __shared__ float ol[64][65];
    const float* qrow = q + ((size_t)(b * S_ + s)) * (NH_ * HD_) + h * HD_;
    qs[lane] = qrow[lane] * 0.125f;
    __syncthreads();
    float qr[64];
#pragma unroll
    for (int d = 0; d < 64; ++d) qr[d] = qs[d];
    float m = -INFINITY, l = 0.f;
    float oacc[64];
#pragma unroll
    for (int d = 0; d < 64; ++d) oacc[d] = 0.f;
    for (int j = lane; j <= s; j += 64) {
        const float* krow = k + ((size_t)(b * S_ + j)) * (NKV_ * HD_) + kvh * HD_;
        float sc = 0.f;
#pragma unroll
        for (int d = 0; d < 64; ++d) sc += qr[d] * krow[d];
        if (sc > m) {
            float rr = expf(m - sc);
            l *= rr;
#pragma unroll
            for (int d = 0; d < 64; ++d) oacc[d] *= rr;
            m = sc;
        }
        float p = expf(sc - m);
        l += p;
        const float* vrow = v + ((size_t)(b * S_ + j)) * (NKV_ * HD_) + kvh * HD_;
#pragma unroll
        for (int d = 0; d < 64; ++d) oacc[d] += p * vrow[d];
    }
    float M = m;
#pragma unroll
    for (int off = 32; off; off >>= 1) M = fmaxf(M, __shfl_xor(M, off));
    float rr = expf(m - M);
    float lw = l * rr;
    float L = lw;
#pragma unroll
    for (int off = 32; off; off >>= 1) L += __shfl_xor(L, off);
#pragma unroll
    for (int d = 0; d < 64; ++d) ol[lane][d] = oacc[d] * rr;
    __syncthreads();
    float sum = 0.f;
#pragma unroll
    for (int i = 0; i < 64; ++i) sum += ol[i][lane];
    o[((size_t)(b * S_ + s)) * (NH_ * HD_) + h * HD_ + lane] = sum / L;
}

// ---------------- zero init: moe buffer + routing counters ----------------
__global__ __launch_bounds__(256) void zero_kernel(float* __restrict__ moe,
                                                   int* __restrict__ c1, int* __restrict__ c2)
{
    int gid = blockIdx.x * 256 + threadIdx.x;
    if (gid < T_ * H_ / 4) ((float4*)moe)[gid] = make_float4(0.f, 0.f, 0.f, 0.f);
    if (gid < E_) { c1[gid] = 0; c2[gid] = 0; }
}

// ---------------- router softmax + top-8 + renorm + histogram ----------------
__global__ __launch_bounds__(64) void topk_kernel(
    const float* __restrict__ logits, float* __restrict__ topw, int* __restrict__ topi,
    int* __restrict__ counts)
{
    int t = blockIdx.x; int e = threadIdx.x;
    float lg = logits[(size_t)t * E_ + e];
    float M = lg;
#pragma unroll
    for (int off = 32; off; off >>= 1) M = fmaxf(M, __shfl_xor(M, off));
    float ex = expf(lg - M);
    float Ssum = ex;
#pragma unroll
    for (int off = 32; off; off >>= 1) Ssum += __shfl_xor(Ssum, off);
    float pcur = ex / Ssum;
    float wsum = 0.f;
    float selw[TOPK_]; int seli[TOPK_];
    for (int r = 0; r < TOPK_; ++r) {
        float v = pcur; int idx = e;
#pragma unroll
        for (int off = 32; off; off >>= 1) {
            float v2 = __shfl_xor(v, off);
            int i2 = __shfl_xor(idx, off);
            if (v2 > v || (v2 == v && i2 < idx)) { v = v2; idx = i2; }
        }
        selw[r] = v; seli[r] = idx; wsum += v;
        if (e == idx) pcur = -1.f;
    }
    if (e < TOPK_) {
        topw[(size_t)t * TOPK_ + e] = selw[e] / wsum;
        topi[(size_t)t * TOPK_ + e] = seli[e];
        atomicAdd(&counts[seli[e]], 1);
    }
}

// ---------------- routing: prefix-sum + tile list (single thread; 64 entries) ----------------
__global__ void route_build_kernel(const int* __restrict__ counts, int* __restrict__ offs,
                                   int* __restrict__ tile_e, int* __restrict__ tile_r,
                                   int* __restrict__ tile_m, int* __restrict__ n_tiles)
{
    if (threadIdx.x == 0 && blockIdx.x == 0) {
        int acc = 0, nt = 0;
        for (int e = 0; e < E_; ++e) {
            offs[e] = acc;
            int c = counts[e];
            for (int p = 0; p < c; p += 64) {
                tile_e[nt] = e; tile_r[nt] = acc + p;
                tile_m[nt] = (c - p < 64) ? (c - p) : 64;
                ++nt;
            }
            acc += c;
        }
        offs[E_] = acc;
        *n_tiles = nt;
    }
}

// ---------------- scatter token/weight into expert-grouped pair lists ----------------
__global__ __launch_bounds__(256) void scatter_kernel(
    const int* __restrict__ topi, const float* __restrict__ topw,
    const int* __restrict__ offs, int* __restrict__ fill,
    int* __restrict__ tok_list, float* __restrict__ wt_list)
{
    int gid = blockIdx.x * 256 + threadIdx.x;
    if (gid >= T_ * TOPK_) return;
    int t = gid >> 3;
    int e = topi[gid];
    int pos = atomicAdd(&fill[e], 1);
    int idx = offs[e] + pos;
    tok_list[idx] = t;
    wt_list[idx] = topw[gid];
}

// ---------------- grouped expert GEMM stage A: P = silu(Y Wg) * (Y Wu) * wt ----------------
__global__ __launch_bounds__(256) void moe_gu_kernel(
    const float* __restrict__ yb, const float* __restrict__ wg, const float* __restrict__ wu,
    const int* __restrict__ tile_e, const int* __restrict__ tile_r, const int* __restrict__ tile_m,
    const int* __restrict__ n_tiles, const int* __restrict__ tok_list,
    const float* __restrict__ wt_list, float* __restrict__ P)
{
    int tl = blockIdx.x;
    if (tl >= *n_tiles) return;
    int e = tile_e[tl], r0 = tile_r[tl], me = tile_m[tl];
    int tid = threadIdx.x;
    __shared__ int   stok[64];
    __shared__ float swt[64];
    __shared__ float As[16][68];
    __shared__ float Bg[16][68];
    __shared__ float Bu[16][68];
    if (tid < 64) {
        int rc = (tid < me) ? tid : (me - 1);
        stok[tid] = tok_list[r0 + rc];
        swt[tid]  = (tid < me) ? wt_list[r0 + tid] : 0.f;
    }
    __syncthreads();
    int tx = tid & 15, ty = tid >> 4;
    int lc = tid & 15, lrb = tid >> 4;
    int nB = tid & 63, kB = tid >> 6;
    for (int c = 0; c < IE_ / 64; ++c) {
        float g[4][4] = {}, u[4][4] = {};
        for (int k0 = 0; k0 < H_; k0 += 16) {
#pragma unroll
            for (int rr = 0; rr < 4; ++rr) {
                int r = lrb + rr * 16;
                As[lc][r] = yb[(size_t)stok[r] * H_ + k0 + lc];
            }
#pragma unroll
            for (int pp = 0; pp < 4; ++pp) {
                int kk = kB + pp * 4;
                size_t bi = ((size_t)e * H_ + k0 + kk) * IE_ + c * 64 + nB;
                Bg[kk][nB] = wg[bi];
                Bu[kk][nB] = wu[bi];
            }
            __syncthreads();
#pragma unroll
            for (int kk = 0; kk < 16; ++kk) {
                float4 av = *(const float4*)&As[kk][ty * 4];
                float4 gv = *(const float4*)&Bg[kk][tx * 4];
                float4 uv = *(const float4*)&Bu[kk][tx * 4];
                float aa[4] = {av.x, av.y, av.z, av.w};
                float gg[4] = {gv.x, gv.y, gv.z, gv.w};
                float uu[4] = {uv.x, uv.y, uv.z, uv.w};
#pragma unroll
                for (int i = 0; i < 4; ++i)
#pragma unroll
                    for (int j = 0; j < 4; ++j) {
                        g[i][j] += aa[i] * gg[j];
                        u[i][j] += aa[i] * uu[j];
                    }
            }
            __syncthreads();
        }
#pragma unroll
        for (int i = 0; i < 4; ++i) {
            int row = ty * 4 + i;
            if (row < me) {
                float wt = swt[row];
                float4 pv;
                float a0 = g[i][0], a1 = g[i][1], a2 = g[i][2], a3 = g[i][3];
                pv.x = a0 / (1.f + expf(-a0)) * u[i][0] * wt;
                pv.y = a1 / (1.f + expf(-a1)) * u[i][1] * wt;
                pv.z = a2 / (1.f + expf(-a2)) * u[i][2] * wt;
                pv.w = a3 / (1.f + expf(-a3)) * u[i][3] * wt;
                *(float4*)&P[(size_t)(r0 + row) * IE_ + c * 64 + tx * 4] = pv;
            }
        }
        __syncthreads();
    }
}

// ---------------- grouped expert GEMM stage B: moe[tok] += P @ Wd ----------------
__global__ __launch_bounds__(256) void moe_down_kernel(
    const float* __restrict__ P, const float* __restrict__ wd,
    const int* __restrict__ tile_e, const int* __restrict__ tile_r, const int* __restrict__ tile_m,
    const int* __restrict__ n_tiles, const int* __restrict__ tok_list,
    float* __restrict__ moe)
{
    int tl = blockIdx.x;
    if (tl >= *n_tiles) return;
    int e = tile_e[tl], r0 = tile_r[tl], me = tile_m[tl];
    int tid = threadIdx.x;
    __shared__ int stok[64];
    __shared__ float As[16][68];
    __shared__ float Bd[16][68];
    if (tid < 64) {
        int rc = (tid < me) ? tid : (me - 1);
        stok[tid] = tok_list[r0 + rc];
    }
    __syncthreads();
    int tx = tid & 15, ty = tid >> 4;
    int lc = tid & 15, lrb = tid >> 4;
    int nB = tid & 63, kB = tid >> 6;
    for (int c = 0; c < H_ / 64; ++c) {
        float d[4][4] = {};
        for (int k0 = 0; k0 < IE_; k0 += 16) {
#pragma unroll
            for (int rr = 0; rr < 4; ++rr) {
                int r = lrb + rr * 16;
                int rc = (r < me) ? r : (me - 1);
                As[lc][r] = P[(size_t)(r0 + rc) * IE_ + k0 + lc];
            }
#pragma unroll
            for (int pp = 0; pp < 4; ++pp) {
                int kk = kB + pp * 4;
                Bd[kk][nB] = wd[((size_t)e * IE_ + k0 + kk) * H_ + c * 64 + nB];
            }
            __syncthreads();
#pragma unroll
            for (int kk = 0; kk < 16; ++kk) {
                float4 av = *(const float4*)&As[kk][ty * 4];
                float4 bv = *(const float4*)&Bd[kk][tx * 4];
                float aa[4] = {av.x, av.y, av.z, av.w};
                float bb[4] = {bv.x, bv.y, bv.z, bv.w};
#pragma unroll
                for (int i = 0; i < 4; ++i)
#pragma unroll
                    for (int j = 0; j < 4; ++j)
                        d[i][j] += aa[i] * bb[j];
            }
            __syncthreads();
        }
#pragma unroll
        for (int i = 0; i < 4; ++i) {
            int row = ty * 4 + i;
            if (row < me) {
                float* dst = &moe[(size_t)stok[row] * H_ + c * 64 + tx * 4];
#pragma unroll
                for (int j = 0; j < 4; ++j) atomicAdd(dst + j, d[i][j]);
            }
        }
        __syncthreads();
    }
}

// ---------------- elementwise silu(g)*u -> g ----------------
__global__ __launch_bounds__(256) void silu_mul_kernel(
    float* __restrict__ g, const float* __restrict__ u, int n)
{
    int i = blockIdx.x * 256 + threadIdx.x;
    if (i < n) {
        float x = g[i];
        g[i] = x / (1.f + expf(-x)) * u[i];
    }
}

// ---------------- final combine ----------------
__global__ __launch_bounds__(256) void combine_kernel(
    const float* __restrict__ hmid, const float* __restrict__ moe,
    const float* __restrict__ shexp, const float* __restrict__ y,
    const float* __restrict__ shg_w, float* __restrict__ out)
{
    int t = blockIdx.x, tid = threadIdx.x;
    __shared__ float red[256];
    float4 yv = ((const float4*)(y + (size_t)t * H_))[tid];
    float4 wv = ((const float4*)shg_w)[tid];
    float part = yv.x * wv.x + yv.y * wv.y + yv.z * wv.z + yv.w * wv.w;
    red[tid] = part; __syncthreads();
    for (int s = 128; s > 0; s >>= 1) { if (tid < s) red[tid] += red[tid + s]; __syncthreads(); }
    float sig = 1.f / (1.f + expf(-red[0]));
    size_t base = (size_t)t * H_ + (size_t)tid * 4;
    float4 hm = *(const float4*)(hmid + base);
    float4 mo = *(const float4*)(moe + base);
    float4 sh = *(const float4*)(shexp + base);
    float4 o;
    o.x = hm.x + mo.x + sig * sh.x;
    o.y = hm.y + mo.y + sig * sh.y;
    o.z = hm.z + mo.z + sig * sh.z;
    o.w = hm.w + mo.w + sig * sh.w;
    ((float4*)out)[(size_t)t * (H_ / 4) + tid] = o;
}

extern "C" void kernel_launch(void* const* d_in, const int* in_sizes, int n_in,
                              void* d_out, int out_size, void* d_ws, size_t ws_size,
                              hipStream_t stream)
{
    const float* hs       = (const float*)d_in[0];
    const float* ln1_w    = (const float*)d_in[1];
    const float* ln2_w    = (const float*)d_in[2];
    const float* q_w      = (const float*)d_in[3];
    const float* q_b      = (const float*)d_in[4];
    const float* k_w      = (const float*)d_in[5];
    const float* k_b      = (const float*)d_in[6];
    const float* v_w      = (const float*)d_in[7];
    const float* v_b      = (const float*)d_in[8];
    const float* o_w      = (const float*)d_in[9];
    const float* gate_w   = (const float*)d_in[10];
    const float* w_gate   = (const float*)d_in[11];
    const float* w_up     = (const float*)d_in[12];
    const float* w_down   = (const float*)d_in[13];
    const float* s_gate_w = (const float*)d_in[14];
    const float* s_up_w   = (const float*)d_in[15];
    const float* s_down_w = (const float*)d_in[16];
    const float* sh_gate_w= (const float*)d_in[17];

    float* wsf = (float*)d_ws;
    size_t offA = 0;                           // xn (T*H) then sg (T*IS); P aliases [0, 8.39M)
    size_t offB = offA + (size_t)T_ * IS_;     // q (T*H) then su (T*IS)
    size_t offC = offB + (size_t)T_ * IS_;     // attn_out (T*H) then shexp (T*H)
    size_t offD = offC + (size_t)T_ * H_;      // k (T*256)
    size_t offE = offD + (size_t)T_ * 256;     // v (T*256)
    size_t offF = offE + (size_t)T_ * 256;     // h_mid (T*H)
    size_t offG = offF + (size_t)T_ * H_;      // y (T*H)
    size_t offH = offG + (size_t)T_ * H_;      // moe_out (T*H)
    size_t offI = offH + (size_t)T_ * H_;      // logits (T*E)
    size_t offJ = offI + (size_t)T_ * E_;      // topw (T*8)
    size_t offK = offJ + (size_t)T_ * TOPK_;   // topi (T*8, int)
    size_t offL = offK + (size_t)T_ * TOPK_;   // counts (64 int)
    size_t offM = offL + E_;                   // fill (64 int)
    size_t offN = offM + E_;                   // offs (65 int)
    size_t offO = offN + E_ + 1;               // tile_e
    size_t offP = offO + MAXTILES;             // tile_r
    size_t offQ = offP + MAXTILES;             // tile_m
    size_t offR = offQ + MAXTILES;             // n_tiles (1 int)
    size_t offS = offR + 1;                    // tok_list (16384 int)
    size_t offT = offS + (size_t)T_ * TOPK_;   // wt_list (16384 float)

    float* xn     = wsf + offA;
    float* sg     = wsf + offA;
    float* Pb     = wsf + offA;   // P: 16384*512 floats = 8.39M, fits in [offA, offE)
    float* qb     = wsf + offB;
    float* su     = wsf + offB;
    float* ao     = wsf + offC;
    float* shexp  = wsf + offC;
    float* kb     = wsf + offD;
    float* vb     = wsf + offE;
    float* hmid   = wsf + offF;
    float* yb     = wsf + offG;
    float* moe    = wsf + offH;
    float* logits = wsf + offI;
    float* topw   = wsf + offJ;
    int*   topi   = (int*)(wsf + offK);
    int*   counts = (int*)(wsf + offL);
    int*   fill   = (int*)(wsf + offM);
    int*   offs   = (int*)(wsf + offN);
    int*   tile_e = (int*)(wsf + offO);
    int*   tile_r = (int*)(wsf + offP);
    int*   tile_m = (int*)(wsf + offQ);
    int*   ntil   = (int*)(wsf + offR);
    int*   tokl   = (int*)(wsf + offS);
    float* wtl    = wsf + offT;

    (void)in_sizes; (void)n_in; (void)out_size; (void)ws_size;

    // ---- attention block ----
    rmsnorm_kernel<<<T_, 256, 0, stream>>>(hs, ln1_w, xn);
    gemm_kernel<1,0><<<dim3(16, 32), 256, 0, stream>>>(xn, q_w, q_b, nullptr, qb, T_, 1024, 1024);
    gemm_kernel<1,0><<<dim3(4, 32), 256, 0, stream>>>(xn, k_w, k_b, nullptr, kb, T_, 256, 1024);
    gemm_kernel<1,0><<<dim3(4, 32), 256, 0, stream>>>(xn, v_w, v_b, nullptr, vb, T_, 256, 1024);
    rope_kernel<<<(T_ * NH_ * 32 + 255) / 256, 256, 0, stream>>>(qb, NH_);
    rope_kernel<<<(T_ * NKV_ * 32 + 255) / 256, 256, 0, stream>>>(kb, NKV_);
    attn_kernel<<<dim3(S_, NH_, B_), 64, 0, stream>>>(qb, kb, vb, ao);
    gemm_kernel<0,1><<<dim3(16, 32), 256, 0, stream>>>(ao, o_w, nullptr, hs, hmid, T_, 1024, 1024);
    // ---- MoE block ----
    rmsnorm_kernel<<<T_, 256, 0, stream>>>(hmid, ln2_w, yb);
    gemm_kernel<0,0><<<dim3(1, 32), 256, 0, stream>>>(yb, gate_w, nullptr, nullptr, logits, T_, 64, 1024);
    zero_kernel<<<(T_ * H_ / 4 + 255) / 256, 256, 0, stream>>>(moe, counts, fill);
    topk_kernel<<<T_, 64, 0, stream>>>(logits, topw, topi, counts);
    route_build_kernel<<<1, 64, 0, stream>>>(counts, offs, tile_e, tile_r, tile_m, ntil);
    scatter_kernel<<<(T_ * TOPK_ + 255) / 256, 256, 0, stream>>>(topi, topw, offs, fill, tokl, wtl);
    moe_gu_kernel<<<MAXTILES, 256, 0, stream>>>(yb, w_gate, w_up, tile_e, tile_r, tile_m,
                                                ntil, tokl, wtl, Pb);
    moe_down_kernel<<<MAXTILES, 256, 0, stream>>>(Pb, w_down, tile_e, tile_r, tile_m,
                                                  ntil, tokl, moe);
    // ---- shared expert (reuses offA/offB after MoE done) ----
    gemm_kernel<0,0><<<dim3(22, 32), 256, 0, stream>>>(yb, s_gate_w, nullptr, nullptr, sg, T_, IS_, 1024);
    gemm_kernel<0,0><<<dim3(22, 32), 256, 0, stream>>>(yb, s_up_w, nullptr, nullptr, su, T_, IS_, 1024);
    silu_mul_kernel<<<(T_ * IS_ + 255) / 256, 256, 0, stream>>>(sg, su, T_ * IS_);
    gemm_kernel<0,0><<<dim3(16, 32), 256, 0, stream>>>(sg, s_down_w, nullptr, nullptr, shexp, T_, H_, IS_);
    // ---- combine ----
    combine_kernel<<<T_, 256, 0, stream>>>(hmid, moe, shexp, yb, sh_gate_w, (float*)d_out);
}